// Round 6
// baseline (1154.408 us; speedup 1.0000x reference)
//
#include <hip/hip_runtime.h>

// Needleman-Wunsch soft-DP (logsumexp-smoothed), linear-domain, pipelined
// across 16 workgroups (1 wave each, 2 rows/thread, 128 rows/WG).
// WAVE-UNIFORM power-of-2 scale oaccF (proven exact in R4). Cross-WG
// boundary in ABSOLUTE log2 domain via IC-coherent (sc0 sc1) stores/loads
// + flag ring with s_waitcnt vmcnt(0) release ordering — no HIP atomics,
// so no buffer_inv / L2 writeback storms (R4's suspected serializer).

constexpr int NDP = 2048;
constexpr int MDP = 2048;
constexpr int G    = 16;            // workgroups (1 wave each)
constexpr int RPW  = 128;           // rows per WG
constexpr int BATCH = 32;           // diagonals per sync batch
constexpr int NB    = 68;           // 68*32 = 2176 = RPW + MDP steps
constexpr int DTOT  = NDP + MDP;    // 4096
constexpr int DVB   = 4224;         // per-WG boundary buffer stride (floats)
constexpr float LOG2E = 1.44269504088896340736f;
constexpr float LN2   = 0.69314718055994530942f;

__device__ __forceinline__ float neginf() { return __int_as_float(0xff800000); }

// IC-coherent primitives (bypass L1 + non-coherent L2; IC is coherence point)
__device__ __forceinline__ void ic_store(float* p, float v) {
  asm volatile("global_store_dword %0, %1, off sc0 sc1" :: "v"(p), "v"(v));
}
__device__ __forceinline__ void ic_store_flag(int* p, int v) {
  asm volatile("s_waitcnt vmcnt(0)\n\tglobal_store_dword %0, %1, off sc0 sc1"
               :: "v"(p), "v"(v));
}
__device__ __forceinline__ float ic_load(const float* p) {
  float r;
  asm volatile("global_load_dword %0, %1, off sc0 sc1\n\ts_waitcnt vmcnt(0)"
               : "=v"(r) : "v"(p));
  return r;
}
__device__ __forceinline__ int ic_load_flag(const int* p) {
  int r;
  asm volatile("global_load_dword %0, %1, off sc0 sc1\n\ts_waitcnt vmcnt(0)"
               : "=v"(r) : "v"(p) : "memory");
  return r;
}

__global__ __launch_bounds__(64)
void nw_pipe(const float* __restrict__ theta, const float* __restrict__ Aptr,
             float* __restrict__ out, float* __restrict__ vbBase,
             int* __restrict__ flags)
{
  const int wg   = blockIdx.x;
  const int lane = threadIdx.x;

  const float A  = Aptr[0];
  const float eA = __builtin_exp2f(A * LOG2E);

  const int S   = wg * RPW + 2;              // first diagonal of this band
  const int rA0 = wg * RPW + 2 * lane;       // 0-indexed row of row "A"
  const int rB0 = rA0 + 1;
  const float* thA_p = theta + (size_t)rA0 * MDP;
  const float* thB_p = theta + (size_t)rB0 * MDP;
  const int endA = rA0 + 1 + MDP;            // last valid diag for row A
  const int endB = endA + 1;

  float* vbMine = vbBase + (size_t)wg * DVB;
  const float* vbProd = vbBase + (size_t)(wg - 1) * DVB;
  int* flagProd = flags + (wg - 1) * 16;
  int* flagMine = flags + wg * 16;
  const int eMaxProd = (wg > 0) ? (wg * RPW + MDP) : -1;

  // per-wave state, all in uniform scale 2^-oaccF
  float WA1 = 0.f, WA2 = 0.f, WB1 = 0.f;
  float upPrev = 0.f;                        // W[rA0-1, d-1] (prev step's upA)
  float bu = 0.f, bd = (wg == 0) ? 1.f : 0.f;  // lane-0 boundary inputs
  float oaccF = 0.f;
  bool  init  = (wg == 0);
  float corner = 0.f;
  float vbReg = neginf();

  // theta register buffers [u][k] (static indices)
  float tba[4][8], tbb[4][8];
#pragma unroll
  for (int u = 0; u < 4; ++u)
#pragma unroll
    for (int k = 0; k < 8; ++k) {
      int d  = S + 8 * u + k;
      int cA = min(max(d - (rA0 + 1) - 1, 0), MDP - 1);
      int cB = min(max(d - (rB0 + 1) - 1, 0), MDP - 1);
      tba[u][k] = thA_p[cA];
      tbb[u][k] = thB_p[cB];
    }

  // batch-0 poll + boundary prefetch (wg>0)
  if (wg > 0) {
    const int E0 = S - 1;
    const int need = min(E0 + 31, eMaxProd);
    while (ic_load_flag(flagProd) < need) __builtin_amdgcn_s_sleep(1);
    int e  = E0 + (lane & 31);
    int eL = min(max(e, 0), eMaxProd);
    float v0 = ic_load(vbProd + eL);
    vbReg = (e <= eMaxProd) ? v0 : neginf();
    float m = vbReg;
#pragma unroll
    for (int sh = 1; sh < 64; sh <<= 1) m = fmaxf(m, __shfl_xor(m, sh, 64));
    if (m > -1e30f) { oaccF = m; init = true; }   // anchor = batch max
    bu = __builtin_exp2f(fminf(__shfl(vbReg, 0, 64) - oaccF, 120.f));
  }

  for (int b = 0; b < NB; ++b) {
    const int dBase = S + BATCH * b;
#pragma unroll
    for (int u = 0; u < 4; ++u) {
#pragma unroll
      for (int k = 0; k < 8; ++k) {
        const int d = dBase + 8 * u + k;
        float upA = __shfl_up(WB1, 1, 64);   // W[rA0-1, d-1] (uniform scale)
        if (lane == 0) upA = bu;
        float dgA = (lane == 0) ? bd : upPrev;   // W[rA0-1, d-2]
        const float tA = __builtin_exp2f(tba[u][k] * LOG2E);
        const float tB = __builtin_exp2f(tbb[u][k] * LOG2E);
        float nA = tA * (eA * (upA + WA1) + dgA);
        float nB = tB * (eA * (WA1 + WB1) + WA2);
        nA = (d <= endA) ? nA : 0.f;         // mask past row end
        nB = (d <= endB) ? nB : 0.f;
        WA2 = WA1; WA1 = nA; WB1 = nB; upPrev = upA;
        if (lane == 63) {                    // publish boundary (absolute log2)
          float vlog = __builtin_log2f(WB1) + oaccF;
          ic_store(vbMine + d, vlog);
          if (d == DTOT) corner = vlog;
        }
        bd = bu;
        if (!(u == 3 && k == 7)) {
          float v = __shfl(vbReg, 8 * u + k + 1, 64);  // static lane index
          bu = __builtin_exp2f(fminf(v - oaccF, 120.f));
        }
      }
      // uniform rescale every 8 steps (exact power-of-2; incl. boundary ins)
      {
        float m = fmaxf(fmaxf(WA1, WB1), fmaxf(WA2, upPrev));
        m = fmaxf(m, fmaxf(bu, bd));
#pragma unroll
        for (int sh = 1; sh < 64; sh <<= 1) m = fmaxf(m, __shfl_xor(m, sh, 64));
        int e = 0;
        if (m > 0.f) e = (int)((__float_as_uint(m) >> 23) & 0xFFu) - 126;
        if (e != 0) {
          WA1 = ldexpf(WA1, -e); WA2 = ldexpf(WA2, -e); WB1 = ldexpf(WB1, -e);
          upPrev = ldexpf(upPrev, -e);
          bu = ldexpf(bu, -e); bd = ldexpf(bd, -e);
          oaccF += (float)e;
        }
      }
      // theta prefetch for next batch, same u-group (32-step distance)
      if (b + 1 < NB) {
#pragma unroll
        for (int k = 0; k < 8; ++k) {
          int d  = dBase + BATCH + 8 * u + k;
          int cA = min(max(d - (rA0 + 1) - 1, 0), MDP - 1);
          int cB = min(max(d - (rB0 + 1) - 1, 0), MDP - 1);
          tba[u][k] = thA_p[cA];
          tbb[u][k] = thB_p[cB];
        }
      }
    }
    // release this batch (data stores drained by vmcnt(0) inside)
    if (wg < G - 1 && lane == 63)
      ic_store_flag(flagMine, dBase + BATCH - 1);
    // acquire next boundary batch
    if (b + 1 < NB && wg > 0) {
      const int E0 = S - 1 + BATCH * (b + 1);
      if (E0 <= eMaxProd) {
        const int need = min(E0 + 31, eMaxProd);
        while (ic_load_flag(flagProd) < need) __builtin_amdgcn_s_sleep(1);
        int e  = E0 + (lane & 31);
        int eL = min(max(e, 0), eMaxProd);
        float v0 = ic_load(vbProd + eL);
        vbReg = (e <= eMaxProd) ? v0 : neginf();
      } else {
        vbReg = neginf();
      }
      if (!init) {
        float m = vbReg;
#pragma unroll
        for (int sh = 1; sh < 64; sh <<= 1) m = fmaxf(m, __shfl_xor(m, sh, 64));
        if (m > -1e30f) { oaccF = m; init = true; }
      }
      bu = __builtin_exp2f(fminf(__shfl(vbReg, 0, 64) - oaccF, 120.f));
    }
  }

  if (wg == G - 1 && lane == 63) out[0] = corner * LN2;   // V[N,M]
}

// ---------- fallback (ws too small): proven single-block kernel ----------
constexpr int NTH = 512;
constexpr int RPT = 4;
constexpr int NWAVE = NTH / 64;

__global__ __launch_bounds__(NTH)
void nw_single(const float* __restrict__ th, const float* __restrict__ Aptr,
               float* __restrict__ out)
{
  const int tid  = threadIdx.x;
  const int lane = tid & 63;
  const int wid  = tid >> 6;
  __shared__ float handW[2][NTH];
  __shared__ float wmax[2][NWAVE];
  const float A  = Aptr[0];
  const float eA = __builtin_exp2f(A * LOG2E);
  const int i_base = tid * RPT + 1;
  float W10=0.f,W11=0.f,W12=0.f,W13=0.f,W20=0.f,W21=0.f,W22=0.f,W23=0.f;
  float nb1 = 0.f, nb2 = (tid == 0) ? 1.f : 0.f;
  int oacc = 0;
  const float* thb = th + (size_t)(i_base - 1) * MDP;
  auto loadTh = [&](int d) -> float4 {
    float4 r;
    int c0 = min(max(d - i_base - 1, 0), MDP - 1);
    int c1 = min(max(d - i_base - 2, 0), MDP - 1);
    int c2 = min(max(d - i_base - 3, 0), MDP - 1);
    int c3 = min(max(d - i_base - 4, 0), MDP - 1);
    r.x = thb[c0]; r.y = thb[(size_t)MDP + c1];
    r.z = thb[(size_t)2 * MDP + c2]; r.w = thb[(size_t)3 * MDP + c3];
    return r;
  };
  float4 thA = loadTh(2), thB = loadTh(3);
  for (int d = 2; d <= DTOT; ++d) {
    float4 thC = loadTh(d + 2);
    float n0 = __builtin_exp2f(thA.x*LOG2E)*(eA*(nb1+W10)+nb2);
    float n1 = __builtin_exp2f(thA.y*LOG2E)*(eA*(W10+W11)+W20);
    float n2 = __builtin_exp2f(thA.z*LOG2E)*(eA*(W11+W12)+W21);
    float n3 = __builtin_exp2f(thA.w*LOG2E)*(eA*(W12+W13)+W22);
    W20=W10;W21=W11;W22=W12;W23=W13;
    int cb = d - i_base - 1;
    W10 = ((unsigned)(cb)     < (unsigned)MDP) ? n0 : 0.f;
    W11 = ((unsigned)(cb - 1) < (unsigned)MDP) ? n1 : 0.f;
    W12 = ((unsigned)(cb - 2) < (unsigned)MDP) ? n2 : 0.f;
    W13 = ((unsigned)(cb - 3) < (unsigned)MDP) ? n3 : 0.f;
    const int buf = d & 1;
    const bool rs = ((d & 1) == 0);
    const int wbuf = (d >> 1) & 1;
    if (rs) {
      float m = fmaxf(fmaxf(W10,W11),fmaxf(W12,W13));
#pragma unroll
      for (int sh = 1; sh < 64; sh <<= 1) m = fmaxf(m, __shfl_xor(m, sh, 64));
      if (lane == 0) wmax[wbuf][wid] = m;
    }
    handW[buf][tid] = W13;
    __syncthreads();
    nb2 = nb1;
    nb1 = (tid == 0) ? 0.f : handW[buf][tid - 1];
    if (rs) {
      float bm = wmax[wbuf][0];
#pragma unroll
      for (int w = 1; w < NWAVE; ++w) bm = fmaxf(bm, wmax[wbuf][w]);
      int e = 0;
      if (bm > 0.f) e = (int)((__float_as_uint(bm) >> 23) & 0xFFu) - 126;
      if (e != 0) {
        W10=ldexpf(W10,-e);W11=ldexpf(W11,-e);W12=ldexpf(W12,-e);W13=ldexpf(W13,-e);
        W20=ldexpf(W20,-e);W21=ldexpf(W21,-e);W22=ldexpf(W22,-e);W23=ldexpf(W23,-e);
        nb1=ldexpf(nb1,-e);nb2=ldexpf(nb2,-e);
        oacc += e;
      }
    }
    thA = thB; thB = thC;
  }
  if (tid == NTH - 1) out[0] = logf(W13) + (float)oacc * LN2;
}

extern "C" void kernel_launch(void* const* d_in, const int* in_sizes, int n_in,
                              void* d_out, int out_size, void* d_ws, size_t ws_size,
                              hipStream_t stream)
{
  const float* theta = (const float*)d_in[0];
  const float* A     = (const float*)d_in[1];
  float* out = (float*)d_out;

  const size_t need = (size_t)G * DVB * sizeof(float) + G * 16 * sizeof(int);
  if (ws_size >= need) {
    float* vb  = (float*)d_ws;
    int* flags = (int*)((char*)d_ws + (size_t)G * DVB * sizeof(float));
    hipLaunchKernelGGL(nw_pipe, dim3(G), dim3(64), 0, stream, theta, A, out, vb, flags);
  } else {
    hipLaunchKernelGGL(nw_single, dim3(1), dim3(NTH), 0, stream, theta, A, out);
  }
}

// Round 7
// 1125.676 us; speedup vs baseline: 1.0255x; 1.0255x over previous
//
#include <hip/hip_runtime.h>

// Needleman-Wunsch soft-DP (logsumexp-smoothed), linear-domain, pipelined
// across 16 workgroups (1 wave each, 2 rows/thread, 128 rows/WG).
// WAVE-UNIFORM power-of-2 scale oaccF. Cross-WG boundary in ABSOLUTE log2
// domain via IC-coherent (sc0 sc1) stores/loads + flag ring.
// R7 fix: force theta prefetch registers RESIDENT — __launch_bounds__(64,1)
// raises the VGPR budget, keep-alive asm pins stop the compiler from
// sinking/rematerializing the prefetch loads to their use points (R6 ran at
// VGPR=76 < needed ~95 -> per-step memory latency on the critical path).

constexpr int NDP = 2048;
constexpr int MDP = 2048;
constexpr int G    = 16;            // workgroups (1 wave each)
constexpr int RPW  = 128;           // rows per WG
constexpr int BATCH = 32;           // diagonals per sync batch
constexpr int NB    = 68;           // 68*32 = 2176 = RPW + MDP steps
constexpr int DTOT  = NDP + MDP;    // 4096
constexpr int DVB   = 4224;         // per-WG boundary buffer stride (floats)
constexpr float LOG2E = 1.44269504088896340736f;
constexpr float LN2   = 0.69314718055994530942f;

__device__ __forceinline__ float neginf() { return __int_as_float(0xff800000); }

// IC-coherent primitives (bypass L1 + non-coherent L2; IC is coherence point)
__device__ __forceinline__ void ic_store(float* p, float v) {
  asm volatile("global_store_dword %0, %1, off sc0 sc1" :: "v"(p), "v"(v));
}
__device__ __forceinline__ void ic_store_flag(int* p, int v) {
  asm volatile("s_waitcnt vmcnt(0)\n\tglobal_store_dword %0, %1, off sc0 sc1"
               :: "v"(p), "v"(v));
}
__device__ __forceinline__ float ic_load(const float* p) {
  float r;
  asm volatile("global_load_dword %0, %1, off sc0 sc1\n\ts_waitcnt vmcnt(0)"
               : "=v"(r) : "v"(p));
  return r;
}
__device__ __forceinline__ int ic_load_flag(const int* p) {
  int r;
  asm volatile("global_load_dword %0, %1, off sc0 sc1\n\ts_waitcnt vmcnt(0)"
               : "=v"(r) : "v"(p) : "memory");
  return r;
}
// keep a value materialized in a VGPR at this program point (anti-sink pin)
__device__ __forceinline__ void pin(float& x) {
  asm volatile("" :: "v"(x));
}

__global__ __launch_bounds__(64, 1)
void nw_pipe(const float* __restrict__ theta, const float* __restrict__ Aptr,
             float* __restrict__ out, float* __restrict__ vbBase,
             int* __restrict__ flags)
{
  const int wg   = blockIdx.x;
  const int lane = threadIdx.x;

  const float A  = Aptr[0];
  const float eA = __builtin_exp2f(A * LOG2E);

  const int S   = wg * RPW + 2;              // first diagonal of this band
  const int rA0 = wg * RPW + 2 * lane;       // 0-indexed row of row "A"
  const int rB0 = rA0 + 1;
  const float* thA_p = theta + (size_t)rA0 * MDP;
  const float* thB_p = theta + (size_t)rB0 * MDP;
  const int endA = rA0 + 1 + MDP;            // last valid diag for row A
  const int endB = endA + 1;

  float* vbMine = vbBase + (size_t)wg * DVB;
  const float* vbProd = vbBase + (size_t)(wg - 1) * DVB;
  int* flagProd = flags + (wg - 1) * 16;
  int* flagMine = flags + wg * 16;
  const int eMaxProd = (wg > 0) ? (wg * RPW + MDP) : -1;

  // per-wave state, all in uniform scale 2^-oaccF
  float WA1 = 0.f, WA2 = 0.f, WB1 = 0.f;
  float upPrev = 0.f;                        // W[rA0-1, d-1] (prev step's upA)
  float bu = 0.f, bd = (wg == 0) ? 1.f : 0.f;  // lane-0 boundary inputs
  float oaccF = 0.f;
  bool  init  = (wg == 0);
  float corner = 0.f;
  float vbReg = neginf();

  // theta register buffers [u][k] (static indices)
  float tba[4][8], tbb[4][8];
#pragma unroll
  for (int u = 0; u < 4; ++u)
#pragma unroll
    for (int k = 0; k < 8; ++k) {
      int d  = S + 8 * u + k;
      int cA = min(max(d - (rA0 + 1) - 1, 0), MDP - 1);
      int cB = min(max(d - (rB0 + 1) - 1, 0), MDP - 1);
      tba[u][k] = thA_p[cA];
      tbb[u][k] = thB_p[cB];
    }

  // batch-0 poll + boundary prefetch (wg>0)
  if (wg > 0) {
    const int E0 = S - 1;
    const int need = min(E0 + 31, eMaxProd);
    while (ic_load_flag(flagProd) < need) __builtin_amdgcn_s_sleep(1);
    int e  = E0 + (lane & 31);
    int eL = min(max(e, 0), eMaxProd);
    float v0 = ic_load(vbProd + eL);
    vbReg = (e <= eMaxProd) ? v0 : neginf();
    float m = vbReg;
#pragma unroll
    for (int sh = 1; sh < 64; sh <<= 1) m = fmaxf(m, __shfl_xor(m, sh, 64));
    if (m > -1e30f) { oaccF = m; init = true; }   // anchor = batch max
    bu = __builtin_exp2f(fminf(__shfl(vbReg, 0, 64) - oaccF, 120.f));
  }

  for (int b = 0; b < NB; ++b) {
    const int dBase = S + BATCH * b;
#pragma unroll
    for (int u = 0; u < 4; ++u) {
#pragma unroll
      for (int k = 0; k < 8; ++k) {
        const int d = dBase + 8 * u + k;
        float upA = __shfl_up(WB1, 1, 64);   // W[rA0-1, d-1] (uniform scale)
        if (lane == 0) upA = bu;
        float dgA = (lane == 0) ? bd : upPrev;   // W[rA0-1, d-2]
        const float tA = __builtin_exp2f(tba[u][k] * LOG2E);
        const float tB = __builtin_exp2f(tbb[u][k] * LOG2E);
        float nA = tA * (eA * (upA + WA1) + dgA);
        float nB = tB * (eA * (WA1 + WB1) + WA2);
        nA = (d <= endA) ? nA : 0.f;         // mask past row end
        nB = (d <= endB) ? nB : 0.f;
        WA2 = WA1; WA1 = nA; WB1 = nB; upPrev = upA;
        if (lane == 63) {                    // publish boundary (absolute log2)
          float vlog = __builtin_log2f(WB1) + oaccF;
          ic_store(vbMine + d, vlog);
          if (d == DTOT) corner = vlog;
        }
        bd = bu;
        if (!(u == 3 && k == 7)) {
          float v = __shfl(vbReg, 8 * u + k + 1, 64);  // static lane index
          bu = __builtin_exp2f(fminf(v - oaccF, 120.f));
        }
      }
      // uniform rescale every 8 steps (exact power-of-2; incl. boundary ins)
      {
        float m = fmaxf(fmaxf(WA1, WB1), fmaxf(WA2, upPrev));
        m = fmaxf(m, fmaxf(bu, bd));
#pragma unroll
        for (int sh = 1; sh < 64; sh <<= 1) m = fmaxf(m, __shfl_xor(m, sh, 64));
        int e = 0;
        if (m > 0.f) e = (int)((__float_as_uint(m) >> 23) & 0xFFu) - 126;
        if (e != 0) {
          WA1 = ldexpf(WA1, -e); WA2 = ldexpf(WA2, -e); WB1 = ldexpf(WB1, -e);
          upPrev = ldexpf(upPrev, -e);
          bu = ldexpf(bu, -e); bd = ldexpf(bd, -e);
          oaccF += (float)e;
        }
      }
      // theta prefetch for next batch, groups 0..2 here (group 3 after poll,
      // so the release's vmcnt(0) doesn't drain freshly-issued loads)
      if (b + 1 < NB && u < 3) {
#pragma unroll
        for (int k = 0; k < 8; ++k) {
          int d  = dBase + BATCH + 8 * u + k;
          int cA = min(max(d - (rA0 + 1) - 1, 0), MDP - 1);
          int cB = min(max(d - (rB0 + 1) - 1, 0), MDP - 1);
          tba[u][k] = thA_p[cA];
          tbb[u][k] = thB_p[cB];
        }
      }
    }
    // release this batch (data stores drained by vmcnt(0) inside)
    if (wg < G - 1 && lane == 63)
      ic_store_flag(flagMine, dBase + BATCH - 1);
    // acquire next boundary batch
    if (b + 1 < NB && wg > 0) {
      const int E0 = S - 1 + BATCH * (b + 1);
      if (E0 <= eMaxProd) {
        const int need = min(E0 + 31, eMaxProd);
        while (ic_load_flag(flagProd) < need) __builtin_amdgcn_s_sleep(1);
        int e  = E0 + (lane & 31);
        int eL = min(max(e, 0), eMaxProd);
        float v0 = ic_load(vbProd + eL);
        vbReg = (e <= eMaxProd) ? v0 : neginf();
      } else {
        vbReg = neginf();
      }
      if (!init) {
        float m = vbReg;
#pragma unroll
        for (int sh = 1; sh < 64; sh <<= 1) m = fmaxf(m, __shfl_xor(m, sh, 64));
        if (m > -1e30f) { oaccF = m; init = true; }
      }
      bu = __builtin_exp2f(fminf(__shfl(vbReg, 0, 64) - oaccF, 120.f));
    }
    if (b + 1 < NB) {
      // group-3 prefetch (post-poll: ~3 u-groups of slack before use)
#pragma unroll
      for (int k = 0; k < 8; ++k) {
        int d  = dBase + BATCH + 24 + k;
        int cA = min(max(d - (rA0 + 1) - 1, 0), MDP - 1);
        int cB = min(max(d - (rB0 + 1) - 1, 0), MDP - 1);
        tba[3][k] = thA_p[cA];
        tbb[3][k] = thB_p[cB];
      }
      // pin groups 0..2 resident here (issued 1-3 u-groups ago; the poll's
      // vmcnt(0) already completed them — pins only forbid sinking/remat)
#pragma unroll
      for (int u = 0; u < 3; ++u)
#pragma unroll
        for (int k = 0; k < 8; ++k) { pin(tba[u][k]); pin(tbb[u][k]); }
    }
  }

  if (wg == G - 1 && lane == 63) out[0] = corner * LN2;   // V[N,M]
}

// ---------- fallback (ws too small): proven single-block kernel ----------
constexpr int NTH = 512;
constexpr int RPT = 4;
constexpr int NWAVE = NTH / 64;

__global__ __launch_bounds__(NTH)
void nw_single(const float* __restrict__ th, const float* __restrict__ Aptr,
               float* __restrict__ out)
{
  const int tid  = threadIdx.x;
  const int lane = tid & 63;
  const int wid  = tid >> 6;
  __shared__ float handW[2][NTH];
  __shared__ float wmax[2][NWAVE];
  const float A  = Aptr[0];
  const float eA = __builtin_exp2f(A * LOG2E);
  const int i_base = tid * RPT + 1;
  float W10=0.f,W11=0.f,W12=0.f,W13=0.f,W20=0.f,W21=0.f,W22=0.f,W23=0.f;
  float nb1 = 0.f, nb2 = (tid == 0) ? 1.f : 0.f;
  int oacc = 0;
  const float* thb = th + (size_t)(i_base - 1) * MDP;
  auto loadTh = [&](int d) -> float4 {
    float4 r;
    int c0 = min(max(d - i_base - 1, 0), MDP - 1);
    int c1 = min(max(d - i_base - 2, 0), MDP - 1);
    int c2 = min(max(d - i_base - 3, 0), MDP - 1);
    int c3 = min(max(d - i_base - 4, 0), MDP - 1);
    r.x = thb[c0]; r.y = thb[(size_t)MDP + c1];
    r.z = thb[(size_t)2 * MDP + c2]; r.w = thb[(size_t)3 * MDP + c3];
    return r;
  };
  float4 thA = loadTh(2), thB = loadTh(3);
  for (int d = 2; d <= DTOT; ++d) {
    float4 thC = loadTh(d + 2);
    float n0 = __builtin_exp2f(thA.x*LOG2E)*(eA*(nb1+W10)+nb2);
    float n1 = __builtin_exp2f(thA.y*LOG2E)*(eA*(W10+W11)+W20);
    float n2 = __builtin_exp2f(thA.z*LOG2E)*(eA*(W11+W12)+W21);
    float n3 = __builtin_exp2f(thA.w*LOG2E)*(eA*(W12+W13)+W22);
    W20=W10;W21=W11;W22=W12;W23=W13;
    int cb = d - i_base - 1;
    W10 = ((unsigned)(cb)     < (unsigned)MDP) ? n0 : 0.f;
    W11 = ((unsigned)(cb - 1) < (unsigned)MDP) ? n1 : 0.f;
    W12 = ((unsigned)(cb - 2) < (unsigned)MDP) ? n2 : 0.f;
    W13 = ((unsigned)(cb - 3) < (unsigned)MDP) ? n3 : 0.f;
    const int buf = d & 1;
    const bool rs = ((d & 1) == 0);
    const int wbuf = (d >> 1) & 1;
    if (rs) {
      float m = fmaxf(fmaxf(W10,W11),fmaxf(W12,W13));
#pragma unroll
      for (int sh = 1; sh < 64; sh <<= 1) m = fmaxf(m, __shfl_xor(m, sh, 64));
      if (lane == 0) wmax[wbuf][wid] = m;
    }
    handW[buf][tid] = W13;
    __syncthreads();
    nb2 = nb1;
    nb1 = (tid == 0) ? 0.f : handW[buf][tid - 1];
    if (rs) {
      float bm = wmax[wbuf][0];
#pragma unroll
      for (int w = 1; w < NWAVE; ++w) bm = fmaxf(bm, wmax[wbuf][w]);
      int e = 0;
      if (bm > 0.f) e = (int)((__float_as_uint(bm) >> 23) & 0xFFu) - 126;
      if (e != 0) {
        W10=ldexpf(W10,-e);W11=ldexpf(W11,-e);W12=ldexpf(W12,-e);W13=ldexpf(W13,-e);
        W20=ldexpf(W20,-e);W21=ldexpf(W21,-e);W22=ldexpf(W22,-e);W23=ldexpf(W23,-e);
        nb1=ldexpf(nb1,-e);nb2=ldexpf(nb2,-e);
        oacc += e;
      }
    }
    thA = thB; thB = thC;
  }
  if (tid == NTH - 1) out[0] = logf(W13) + (float)oacc * LN2;
}

extern "C" void kernel_launch(void* const* d_in, const int* in_sizes, int n_in,
                              void* d_out, int out_size, void* d_ws, size_t ws_size,
                              hipStream_t stream)
{
  const float* theta = (const float*)d_in[0];
  const float* A     = (const float*)d_in[1];
  float* out = (float*)d_out;

  const size_t need = (size_t)G * DVB * sizeof(float) + G * 16 * sizeof(int);
  if (ws_size >= need) {
    float* vb  = (float*)d_ws;
    int* flags = (int*)((char*)d_ws + (size_t)G * DVB * sizeof(float));
    hipLaunchKernelGGL(nw_pipe, dim3(G), dim3(64), 0, stream, theta, A, out, vb, flags);
  } else {
    hipLaunchKernelGGL(nw_single, dim3(1), dim3(NTH), 0, stream, theta, A, out);
  }
}